// Round 2
// baseline (382.317 us; speedup 1.0000x reference)
//
#include <hip/hip_runtime.h>
#include <hip/hip_bf16.h>
#include <math.h>

typedef short short8 __attribute__((ext_vector_type(8)));
typedef float f32x4  __attribute__((ext_vector_type(4)));

#define N_SEQ 8192
#define D_CH  512

__device__ __forceinline__ unsigned short f32_to_bf16_bits(float f) {
    union { float f; unsigned int u; } v; v.f = f;
    unsigned int u = v.u;
    unsigned int r = u + 0x7FFFu + ((u >> 16) & 1u);   // RNE
    return (unsigned short)(r >> 16);
}

// ---------------- pre-pass: transpose + cast to bf16 ----------------
// x (4,8192,512) f32 -> xT (4,512,8192) bf16 ; t (8192,512) -> tT (512,8192)
__global__ __launch_bounds__(256) void transpose_cast_kernel(
    const float* __restrict__ x, const float* __restrict__ t,
    unsigned short* __restrict__ xT, unsigned short* __restrict__ tT) {
  __shared__ float tile[64][65];
  int blk = blockIdx.x;
  int bat = blk >> 10;        // 1024 tiles (128 i-tiles * 8 d-tiles) per "batch"
  int rem = blk & 1023;
  int i0 = (rem >> 3) << 6;
  int d0 = (rem & 7) << 6;
  const float* src; unsigned short* dst;
  if (bat < 4) { src = x + (size_t)bat * N_SEQ * D_CH; dst = xT + (size_t)bat * D_CH * N_SEQ; }
  else         { src = t;                              dst = tT; }
  int tx = threadIdx.x & 63, ty = threadIdx.x >> 6;
  #pragma unroll
  for (int r = ty; r < 64; r += 4)
    tile[r][tx] = src[(size_t)(i0 + r) * D_CH + (d0 + tx)];
  __syncthreads();
  #pragma unroll
  for (int r = ty; r < 64; r += 4)
    dst[(size_t)(d0 + r) * N_SEQ + (i0 + tx)] = f32_to_bf16_bits(tile[tx][r]);
}

// ---------------- main kernel ----------------
// Per wave: one channel d, 16 accumulators (g=0..3 col-groups, k=0..3 lag
// sub-shifts) covering 1024 contiguous output rows x 4 batches.
// D[p][c] += sum_q t[l+16k+p-q] * x[bcol, c_abs + q - l],  c_abs = base+64*(4g+sl)
// Loop l = -32, 0, 32, ..., base+960: lag coverage [16k+p-63, i] ⊇ [0, i].
constexpr int XSLOTS   = 1024;             // circular x rows per batch
constexpr int XLDS_B   = 4 * XSLOTS * 2;   // 8192 B
constexpr int TSTRIDE  = 272;              // bytes per reversed-t copy (bank spread)
constexpr int TLDS_B   = 8 * TSTRIDE;      // 2176 B
constexpr int WAVE_LDS = XLDS_B + TLDS_B;  // 10368 B

__device__ __forceinline__ int swz_x(int byte) {
  // spread (slot bits 7-8, batch bit 11) into 16B-granule bits 4-6
  int s = ((byte >> 7) & 3) | ((byte >> 9) & 4);
  return byte ^ (s << 4);
}

__global__ __launch_bounds__(256) void tno_conv_kernel(
    const unsigned short* __restrict__ xT, const unsigned short* __restrict__ tT,
    float* __restrict__ out) {
  __shared__ __align__(16) char lds_all[4 * WAVE_LDS];
  const int tid  = threadIdx.x;
  const int wv   = tid >> 6;
  const int lane = tid & 63;
  char* ldsX = lds_all + wv * WAVE_LDS;
  char* ldsT = ldsX + XLDS_B;
  const int d = blockIdx.x;

  // lane constants
  const int m      = lane & 15;          // A row index / D col index
  const int kb     = (lane >> 4) << 3;   // K-block base: 0,8,16,24
  const int bcol   = m & 3;              // batch of this D/B column
  const int sl     = m >> 2;             // s_local of this D/B column
  const int rA     = m & 7;              // reversed-t copy used by A reads
  const int aConst = kb - (m & 8);       // A slot = (aConst - L_k) & 127
  // stage_x lane mapping: batch = lane>>4, row-pair = 2*(lane&15)
  const int sxB   = lane >> 4;
  const int sxRow = (lane & 15) << 1;
  const unsigned short* xTb = xT + (((size_t)sxB * D_CH + d) << 13);
  // stage_t lane mapping: value j = lane&31, copies 4*(lane>>5)+0..3
  const int stJ  = lane & 31;
  const int stR0 = (lane >> 5) << 2;
  const unsigned short* tTd = tT + ((size_t)d << 13);

  #pragma unroll 1
  for (int region = 0; region < 2; ++region) {
    const int base = (region == 0) ? (wv << 10) : (7168 - (wv << 10));

    f32x4 acc[4][4];
    #pragma unroll
    for (int g = 0; g < 4; ++g)
      #pragma unroll
      for (int k = 0; k < 4; ++k)
        acc[g][k] = (f32x4){0.f, 0.f, 0.f, 0.f};

    // stage 32 x-rows [base-ls, base-ls+32) x 4 batches into circular LDS
    auto stage_x = [&](int ls) {
      int row = base - ls + sxRow;
      unsigned int v = 0;
      if (row >= 0) v = *reinterpret_cast<const unsigned int*>(xTb + row);
      int byte = (sxB << 11) + ((row & (XSLOTS - 1)) << 1);
      *reinterpret_cast<unsigned int*>(ldsX + swz_x(byte)) = v;
    };
    // stage t[ls+64 .. ls+95] reversed into all 8 copies
    auto stage_t = [&](int ls) {
      int idx = ls + 64 + stJ;
      unsigned short v = 0;
      if (idx >= 0 && idx < N_SEQ) v = tTd[idx];
      #pragma unroll
      for (int c = 0; c < 4; ++c) {
        int r = stR0 + c;
        int slot = (r - idx) & 127;
        *reinterpret_cast<unsigned short*>(ldsT + r * TSTRIDE + (slot << 1)) = v;
      }
    };

    // prologue: x rows [base+32, base+1023], t idx [-64, 31]
    for (int ls = -992; ls <= -32; ls += 32) stage_x(ls);
    stage_t(-128); stage_t(-96); stage_t(-64);

    const int lend = base + 960;
    for (int l = -32; l <= lend; l += 32) {
      short8 af[4];
      #pragma unroll
      for (int k = 0; k < 4; ++k) {
        int slot = (aConst - l - (k << 4)) & 127;   // == 0 mod 8, no wrap
        af[k] = *reinterpret_cast<const short8*>(ldsT + rA * TSTRIDE + (slot << 1));
      }
      #pragma unroll
      for (int g = 0; g < 4; ++g) {
        if (l <= base + (g << 8) + 223) {           // group still causal-active
          int rowoff = (((g << 2) + sl) << 6) + kb; // 64*(4g+sl)+kb
          int slot = (base + rowoff - l) & (XSLOTS - 1);
          int byte = (bcol << 11) + (slot << 1);
          short8 bf = *reinterpret_cast<const short8*>(ldsX + swz_x(byte));
          #pragma unroll
          for (int k = 0; k < 4; ++k)
            acc[g][k] = __builtin_amdgcn_mfma_f32_16x16x32_bf16(af[k], bf, acc[g][k], 0, 0, 0);
        }
      }
      stage_x(l + 32);   // rows overwritten are provably dead
      stage_t(l);        // idx [l+64, l+95] for next iteration
    }

    // epilogue: gelu(tanh approx, matching jax.nn.gelu default) + store
    #pragma unroll
    for (int g = 0; g < 4; ++g) {
      #pragma unroll
      for (int k = 0; k < 4; ++k) {
        #pragma unroll
        for (int r = 0; r < 4; ++r) {
          int i = base + (((g << 2) + sl) << 6) + (k << 4) + ((lane >> 4) << 2) + r;
          float v = acc[g][k][r];
          float y = 0.5f * v * (1.f + tanhf(0.79788456080286535588f * (v + 0.044715f * v * v * v)));
          out[(((size_t)bcol << 13) + (size_t)i) * D_CH + d] = y;
        }
      }
    }
  }
}

extern "C" void kernel_launch(void* const* d_in, const int* in_sizes, int n_in,
                              void* d_out, int out_size, void* d_ws, size_t ws_size,
                              hipStream_t stream) {
  const float* x = (const float*)d_in[0];
  const float* t = (const float*)d_in[1];
  float* out = (float*)d_out;
  // workspace layout: xT bf16 (4*512*8192 = 32MB) | tT bf16 (512*8192 = 8MB)
  unsigned short* xT = (unsigned short*)d_ws;
  unsigned short* tT = xT + (size_t)4 * D_CH * N_SEQ;

  hipLaunchKernelGGL(transpose_cast_kernel, dim3(5 * 1024), dim3(256), 0, stream,
                     x, t, xT, tT);
  hipLaunchKernelGGL(tno_conv_kernel, dim3(D_CH), dim3(256), 0, stream,
                     xT, tT, out);
}

// Round 3
// 205.729 us; speedup vs baseline: 1.8583x; 1.8583x over previous
//
#include <hip/hip_runtime.h>
#include <hip/hip_bf16.h>
#include <math.h>

typedef short short8 __attribute__((ext_vector_type(8)));
typedef float f32x4  __attribute__((ext_vector_type(4)));

#define N_SEQ 8192
#define D_CH  512

__device__ __forceinline__ unsigned short f32_to_bf16_bits(float f) {
    union { float f; unsigned int u; } v; v.f = f;
    unsigned int u = v.u;
    unsigned int r = u + 0x7FFFu + ((u >> 16) & 1u);   // RNE
    return (unsigned short)(r >> 16);
}

// ---------------- pre-pass: transpose + cast to bf16 ----------------
__global__ __launch_bounds__(256) void transpose_cast_kernel(
    const float* __restrict__ x, const float* __restrict__ t,
    unsigned short* __restrict__ xT, unsigned short* __restrict__ tT) {
  __shared__ float tile[64][65];
  int blk = blockIdx.x;
  int bat = blk >> 10;
  int rem = blk & 1023;
  int i0 = (rem >> 3) << 6;
  int d0 = (rem & 7) << 6;
  const float* src; unsigned short* dst;
  if (bat < 4) { src = x + (size_t)bat * N_SEQ * D_CH; dst = xT + (size_t)bat * D_CH * N_SEQ; }
  else         { src = t;                              dst = tT; }
  int tx = threadIdx.x & 63, ty = threadIdx.x >> 6;
  #pragma unroll
  for (int r = ty; r < 64; r += 4)
    tile[r][tx] = src[(size_t)(i0 + r) * D_CH + (d0 + tx)];
  __syncthreads();
  #pragma unroll
  for (int r = ty; r < 64; r += 4)
    dst[(size_t)(d0 + r) * N_SEQ + (i0 + tx)] = f32_to_bf16_bits(tile[tx][r]);
}

// ---------------- output transpose: (d,b,i) -> (b,i,d) ----------------
__global__ __launch_bounds__(256) void transpose_out_kernel(
    const float* __restrict__ src, float* __restrict__ dst) {
  __shared__ float tile[64][65];
  int blk = blockIdx.x;
  int b   = blk >> 10;
  int rem = blk & 1023;          // 8 d-tiles x 128 i-tiles
  int d0 = (rem & 7) << 6;
  int i0 = (rem >> 3) << 6;
  int tx = threadIdx.x & 63, ty = threadIdx.x >> 6;
  #pragma unroll
  for (int r = ty; r < 64; r += 4)
    tile[r][tx] = src[((size_t)(d0 + r) * 4 + b) * N_SEQ + i0 + tx];
  __syncthreads();
  #pragma unroll
  for (int r = ty; r < 64; r += 4)
    dst[((size_t)b * N_SEQ + i0 + r) * D_CH + d0 + tx] = tile[tx][r];
}

// ---------------- main kernel ----------------
// x ring layout (chunk-interleaved): slot s, batch b at
//   byte = ((s>>3)<<6) | (b<<4) | ((s&7)<<1)    (4096 slots*2B*... = 8192 B)
// t rings: 8 reversed copies, copy r at r*272, slot (r-idx)&127.
constexpr int XLDS_B   = 8192;
constexpr int TSTRIDE  = 272;
constexpr int TLDS_B   = 8 * TSTRIDE;      // 2176
constexpr int WAVE_LDS = XLDS_B + TLDS_B;  // 10368

template<int DMAJOR>
__global__ __launch_bounds__(256) void tno_conv_kernel(
    const unsigned short* __restrict__ xT, const unsigned short* __restrict__ tT,
    float* __restrict__ outp) {
  __shared__ __align__(16) char lds_all[4 * WAVE_LDS];
  const int tid  = threadIdx.x;
  const int wv   = tid >> 6;
  const int lane = tid & 63;
  char* ldsX = lds_all + wv * WAVE_LDS;
  char* ldsT = ldsX + XLDS_B;
  const int d = blockIdx.x;

  const int m      = lane & 15;
  const int kb     = (lane >> 4) << 3;
  const int bcol   = m & 3;
  const int sl     = m >> 2;
  const int rA     = m & 7;
  const int aConst = kb - (m & 8);
  const char* tb   = ldsT + rA * TSTRIDE;     // A-frag base (per lane)
  const char* ldsXb = ldsX + (bcol << 4);     // B-read base (per lane)

  const int sxB   = lane >> 4;
  const int sxRow = (lane & 15) << 1;
  char* ldsXsb = ldsX + (sxB << 4);
  const unsigned short* xTb = xT + (((size_t)sxB * D_CH + d) << 13);

  const int stJ  = lane & 31;
  const int stR0 = (lane >> 5) << 2;
  char* twbase = ldsT + stR0 * TSTRIDE;
  const unsigned short* tTd = tT + ((size_t)d << 13);

  #pragma unroll 1
  for (int region = 0; region < 2; ++region) {
    const int base = (region == 0) ? (wv << 10) : (7168 - (wv << 10));

    f32x4 acc[4][4];
    #pragma unroll
    for (int g = 0; g < 4; ++g)
      #pragma unroll
      for (int k = 0; k < 4; ++k)
        acc[g][k] = (f32x4){0.f, 0.f, 0.f, 0.f};

    // ---- prologue staging ----
    auto stage_x_pro = [&](int ls) {
      int row = base - ls + sxRow;
      unsigned int v = 0;
      if (row >= 0) v = *reinterpret_cast<const unsigned int*>(xTb + row);
      int s = row & 1023;
      int byte = ((s >> 3) << 6) | ((s & 7) << 1);
      *reinterpret_cast<unsigned int*>(ldsXsb + byte) = v;
    };
    auto stage_t_pro = [&](int ls) {
      int idx = ls + 64 + stJ;
      unsigned short v = 0;
      if (idx >= 0 && idx < N_SEQ) v = tTd[idx];
      #pragma unroll
      for (int c = 0; c < 4; ++c) {
        int r = stR0 + c;
        int slot = (r - idx) & 127;
        *reinterpret_cast<unsigned short*>(ldsT + r * TSTRIDE + (slot << 1)) = v;
      }
    };
    for (int ls = -992; ls <= -32; ls += 32) stage_x_pro(ls);
    stage_t_pro(-128); stage_t_pro(-96); stage_t_pro(-64);

    // ---- iteration state (all incremental) ----
    int aC = (aConst & 127) << 1;                     // af2 byte offset at l=-32
    short8 af0 = *reinterpret_cast<const short8*>(tb + ((aC + 64) & 255));
    short8 af1 = *reinterpret_cast<const short8*>(tb + ((aC + 32) & 255));

    int xb[4];
    #pragma unroll
    for (int g = 0; g < 4; ++g)
      xb[g] = ((base + ((((g << 2) + sl) << 6) + kb) + 32) & 1023) << 3;

    int xrow = base + sxRow;                          // row staged at l=-32
    const unsigned short* xp = xTb + xrow;
    int wb; { int s = xrow & 1023; wb = ((s >> 3) << 6) | ((s & 7) << 1); }

    int tidx = 32 + stJ;                              // t idx staged at l=-32
    const unsigned short* tp = tTd + tidx;
    int tw0 = ((stR0 + 0 - tidx) & 127) << 1;
    int tw1 = ((stR0 + 1 - tidx) & 127) << 1;
    int tw2 = ((stR0 + 2 - tidx) & 127) << 1;
    int tw3 = ((stR0 + 3 - tidx) & 127) << 1;

#define CONV_ITER(GMIN)                                                         \
  {                                                                             \
    short8 af2 = *reinterpret_cast<const short8*>(tb + aC);                     \
    short8 af3 = *reinterpret_cast<const short8*>(tb + ((aC - 32) & 255));      \
    unsigned int xv = 0;                                                        \
    if (xrow >= 0) xv = *reinterpret_cast<const unsigned int*>(xp);             \
    unsigned int tv = 0;                                                        \
    if (tidx < N_SEQ) tv = (unsigned int)(*tp);                                 \
    _Pragma("unroll")                                                           \
    for (int g = 0; g < 4; ++g) {                                               \
      if (g >= (GMIN)) {                                                        \
        short8 bf = *reinterpret_cast<const short8*>(ldsXb + xb[g]);            \
        acc[g][0] = __builtin_amdgcn_mfma_f32_16x16x32_bf16(af0, bf, acc[g][0], 0, 0, 0); \
        acc[g][1] = __builtin_amdgcn_mfma_f32_16x16x32_bf16(af1, bf, acc[g][1], 0, 0, 0); \
        acc[g][2] = __builtin_amdgcn_mfma_f32_16x16x32_bf16(af2, bf, acc[g][2], 0, 0, 0); \
        acc[g][3] = __builtin_amdgcn_mfma_f32_16x16x32_bf16(af3, bf, acc[g][3], 0, 0, 0); \
        xb[g] = (xb[g] - 256) & 8191;                                           \
      }                                                                         \
    }                                                                           \
    *reinterpret_cast<unsigned int*>(ldsXsb + wb) = xv;                         \
    unsigned short tvs = (unsigned short)tv;                                    \
    *reinterpret_cast<unsigned short*>(twbase + tw0 + 0 * TSTRIDE) = tvs;       \
    *reinterpret_cast<unsigned short*>(twbase + tw1 + 1 * TSTRIDE) = tvs;       \
    *reinterpret_cast<unsigned short*>(twbase + tw2 + 2 * TSTRIDE) = tvs;       \
    *reinterpret_cast<unsigned short*>(twbase + tw3 + 3 * TSTRIDE) = tvs;       \
    af0 = af2; af1 = af3;                                                       \
    aC = (aC - 64) & 255;                                                       \
    xrow -= 32; xp -= 32;                                                       \
    wb = (wb - 256) & 8191;                                                     \
    tidx += 32; tp += 32;                                                       \
    tw0 = (tw0 - 64) & 255; tw1 = (tw1 - 64) & 255;                             \
    tw2 = (tw2 - 64) & 255; tw3 = (tw3 - 64) & 255;                             \
  }

    int l = -32;
    for (; l <= base + 192; l += 32) CONV_ITER(0)
    for (; l <= base + 448; l += 32) CONV_ITER(1)
    for (; l <= base + 704; l += 32) CONV_ITER(2)
    for (; l <= base + 960; l += 32) CONV_ITER(3)
#undef CONV_ITER

    // ---- epilogue: gelu + store ----
    if (DMAJOR) {
      float* op = outp + ((((size_t)d << 2) + bcol) << 13) + base + (sl << 6) + ((lane >> 4) << 2);
      #pragma unroll
      for (int g = 0; g < 4; ++g)
        #pragma unroll
        for (int k = 0; k < 4; ++k)
          #pragma unroll
          for (int r = 0; r < 4; ++r) {
            float v = acc[g][k][r];
            float y = 0.5f * v * (1.f + tanhf(0.79788456080286535588f * (v + 0.044715f * v * v * v)));
            op[(g << 8) + (k << 4) + r] = y;
          }
    } else {
      #pragma unroll
      for (int g = 0; g < 4; ++g)
        #pragma unroll
        for (int k = 0; k < 4; ++k)
          #pragma unroll
          for (int r = 0; r < 4; ++r) {
            int i = base + (((g << 2) + sl) << 6) + (k << 4) + ((lane >> 4) << 2) + r;
            float v = acc[g][k][r];
            float y = 0.5f * v * (1.f + tanhf(0.79788456080286535588f * (v + 0.044715f * v * v * v)));
            outp[(((size_t)bcol << 13) + (size_t)i) * D_CH + d] = y;
          }
    }
  }
}

extern "C" void kernel_launch(void* const* d_in, const int* in_sizes, int n_in,
                              void* d_out, int out_size, void* d_ws, size_t ws_size,
                              hipStream_t stream) {
  const float* x = (const float*)d_in[0];
  const float* t = (const float*)d_in[1];
  float* out = (float*)d_out;

  const size_t xT_elems = (size_t)4 * D_CH * N_SEQ;       // bf16
  const size_t tT_elems = (size_t)D_CH * N_SEQ;           // bf16
  unsigned short* xT = (unsigned short*)d_ws;
  unsigned short* tT = xT + xT_elems;
  float* ows = (float*)(tT + tT_elems);
  const size_t need = xT_elems * 2 + tT_elems * 2 + (size_t)4 * N_SEQ * D_CH * 4;
  const bool dmaj = (ws_size >= need);

  hipLaunchKernelGGL(transpose_cast_kernel, dim3(5 * 1024), dim3(256), 0, stream,
                     x, t, xT, tT);
  if (dmaj) {
    hipLaunchKernelGGL((tno_conv_kernel<1>), dim3(D_CH), dim3(256), 0, stream,
                       xT, tT, ows);
    hipLaunchKernelGGL(transpose_out_kernel, dim3(4096), dim3(256), 0, stream,
                       ows, out);
  } else {
    hipLaunchKernelGGL((tno_conv_kernel<0>), dim3(D_CH), dim3(256), 0, stream,
                       xT, tT, out);
  }
}